// Round 3
// baseline (241.450 us; speedup 1.0000x reference)
//
#include <hip/hip_runtime.h>

typedef _Float16 f16;
typedef __attribute__((ext_vector_type(4))) _Float16 f16x4;
typedef __attribute__((ext_vector_type(8))) _Float16 f16x8;
typedef __attribute__((ext_vector_type(4))) float f32x4;
typedef __attribute__((ext_vector_type(16))) float f32x16;
typedef unsigned int u32;

#define BB 32
#define LL 1024
#define DD 256

#define VMCNT(N) asm volatile("s_waitcnt vmcnt(" #N ")" ::: "memory")
#define LGKMCNT0 asm volatile("s_waitcnt lgkmcnt(0)" ::: "memory")

// async global->LDS, 16B per lane, dst = ldsbase + lane*16 (wave-uniform base)
__device__ __forceinline__ void async_copy16(const f16* g, f16* l) {
  __builtin_amdgcn_global_load_lds(
      (const __attribute__((address_space(1))) u32*)(const void*)g,
      (__attribute__((address_space(3))) u32*)(void*)l, 16, 0, 0);
}

// pack two f32 -> f16x2 in a u32 (v_cvt_pkrtz_f16_f32)
__device__ __forceinline__ u32 pack_pkrtz(float a, float b) {
  auto pk = __builtin_amdgcn_cvt_pkrtz(a, b);  // __fp16 ext_vector(2)
  u32 w;
  __builtin_memcpy(&w, &pk, 4);
  return w;
}

// ---------------------------------------------------------------------------
// Transpose + fp32->fp16 (used only for the tiny W^T).
// ---------------------------------------------------------------------------
__global__ __launch_bounds__(256) void transpose_to_f16(
    const float* __restrict__ X0, f16* __restrict__ Y0,
    const float* __restrict__ X1, f16* __restrict__ Y1,
    int L, int D, int nbPerInput) {
  __shared__ float T[64][68];
  const int tid = threadIdx.x;
  int bz = blockIdx.z;
  const float* X = X0;
  f16* Y = Y0;
  int b = bz;
  if (bz >= nbPerInput) { X = X1; Y = Y1; b = bz - nbPerInput; }
  const int l0 = blockIdx.x * 64, d0 = blockIdx.y * 64;
  const size_t baseX = (size_t)b * L * D;
#pragma unroll
  for (int pass = 0; pass < 4; ++pass) {
    int r = (tid >> 4) + pass * 16;
    int c = (tid & 15) * 4;
    float4 v = *(const float4*)&X[baseX + (size_t)(l0 + r) * D + d0 + c];
    *(float4*)&T[r][c] = v;
  }
  __syncthreads();
  const size_t baseY = (size_t)b * D * L;
#pragma unroll
  for (int pass = 0; pass < 2; ++pass) {
    int dr = (tid >> 3) + pass * 32;
    int lc = (tid & 7) * 8;
    f16x8 o;
#pragma unroll
    for (int j = 0; j < 8; ++j) o[j] = (f16)T[lc + j][dr];
    *(f16x8*)&Y[baseY + (size_t)(d0 + dr) * L + l0 + lc] = o;
  }
}

// ---------------------------------------------------------------------------
// Projection: F = tanh(A @ W) (f16, CHUNK-SWIZZLED rows) + V^T emit in
// TILE-MAJOR layout [b][qtile][d][32q] with j-swizzle baked into DRAM.
// All scratch stores are linear 1-KB wave transactions (no scattered writes).
// W frags read straight from L2 (no Wts LDS) -> 33 KB LDS, 3 barriers,
// 3 blocks/CU.
//
// F swizzle:  row m stores data-chunk c (16B) at chunk slot c ^ (m&15).
// Vt swizzle: tile T, row d stores q-subchunk j (8 f16) at slot j^((d>>1)&3).
// ---------------------------------------------------------------------------
__global__ __launch_bounds__(256, 3) void proj_mfma(
    const float* __restrict__ Pin, const float* __restrict__ Hin,
    const f16* __restrict__ Wt, f16* __restrict__ Fp, f16* __restrict__ Fh,
    f16* __restrict__ Vtp, f16* __restrict__ Vth) {
  __shared__ f16 As[64][264];  // 33 KB; 264 pad: 16B-aligned rows, b128-clean
  const int tid = threadIdx.x;
  const int wv = tid >> 6, lane = tid & 63;
  const int l32 = lane & 31, half = lane >> 5;
  const int wm = wv >> 1, wn = wv & 1;
  const float* A = blockIdx.z ? Hin : Pin;
  f16* F = blockIdx.z ? Fh : Fp;
  f16* VtO = blockIdx.z ? Vth : Vtp;
  const int m0 = blockIdx.x * 64;

  // stage full A tile (64 x 256) fp32 -> f16, fully coalesced rows
  {
    const int r = tid >> 4;         // 0..15
    const int c4 = (tid & 15) * 4;  // 0..60
#pragma unroll
    for (int pp = 0; pp < 4; ++pp)
#pragma unroll
      for (int ch = 0; ch < 4; ++ch) {
        float4 v =
            *(const float4*)&A[(size_t)(m0 + r + pp * 16) * 256 + ch * 64 + c4];
        f16x4 h4;
        h4[0] = (f16)v.x; h4[1] = (f16)v.y; h4[2] = (f16)v.z; h4[3] = (f16)v.w;
        *(f16x4*)&As[r + pp * 16][ch * 64 + c4] = h4;
      }
  }
  __syncthreads();

  // hoist all 16 A-frags (32x32x16: m=l32, k=half*8+j) -- reused for all nc
  f16x8 af[16];
#pragma unroll
  for (int ks = 0; ks < 16; ++ks)
    af[ks] = *(const f16x8*)&As[wm * 32 + l32][ks * 16 + half * 8];

  // V^T emit, tile-major + baked swizzle: per instr 16 d-rows x 64B = linear
  // 1 KB store. LDS column reads are conflict-free (verified bank map).
  {
    const int bI = m0 >> 10;
    const int T = ((m0 & 1023) >> 5) + (wv & 1);  // this wave's q-tile
    const int dg = (wv >> 1) * 128;               // this wave's d-range
    const int jp = lane & 3;                      // stored slot j'
    const int j = jp ^ ((lane >> 3) & 3);         // data subchunk j
    const int rloc = (wv & 1) * 32 + j * 8;       // As row base (q_local)
#pragma unroll
    for (int e = 0; e < 8; ++e) {
      int d = dg + e * 16 + (lane >> 2);
      f16x8 ov;
#pragma unroll
      for (int jj = 0; jj < 8; ++jj) ov[jj] = As[rloc + jj][d];
      *(f16x8*)&VtO[((size_t)(bI * 32 + T) * 256 + d) * 32 + jp * 8] = ov;
    }
  }
  __syncthreads();  // all As reads done before overwrite

  // nc loop: W frags from global (L2-resident 131 KB), MFMA, tanh -> As bounce
#pragma unroll
  for (int nc = 0; nc < 4; ++nc) {
    f32x16 acc = (f32x16)(0.f);
#pragma unroll
    for (int ks = 0; ks < 16; ++ks) {
      f16x8 wf = *(const f16x8*)&Wt[(size_t)(nc * 64 + wn * 32 + l32) * 256 +
                                    ks * 16 + half * 8];
      acc = __builtin_amdgcn_mfma_f32_32x32x16_f16(af[ks], wf, acc, 0, 0, 0);
    }
#pragma unroll
    for (int r = 0; r < 16; ++r) {
      float xv = acc[r];
      float e2 = __expf(2.f * xv);
      float th = 1.f - 2.f / (e2 + 1.f);
      As[wm * 32 + (r & 3) + 8 * (r >> 2) + 4 * half]
        [nc * 64 + wn * 32 + l32] = (f16)th;
    }
  }
  __syncthreads();

  // F store: chunk-swizzled rows, linear 1-KB wave stores (2 rows/instr)
#pragma unroll
  for (int e = 0; e < 8; ++e) {
    int lm = wv * 16 + e * 2 + (lane >> 5);
    int cp = lane & 31;            // stored chunk slot
    int c = cp ^ (lm & 15);        // data chunk held there
    f16x8 ov = *(const f16x8*)&As[lm][c * 8];
    *(f16x8*)&F[(size_t)(m0 + lm) * 256 + cp * 8] = ov;
  }
}

// ---------------------------------------------------------------------------
// Flash alignment, 32x32x16 MFMA, transposed formulation:
//   S^T = K Q^T  (A=K frags from LDS, B=Q frags in regs)
//   O^T = V^T P^T (A=V^T frags from LDS, B=P^T built by cross-half shuffle)
// K/V staging is now LINEAR CONTIGUOUS 1-KB DMA per instr (swizzles baked
// into F / Vt by proj); fragment ds_read_b128 are bank-uniform via the
// baked XOR swizzles. QK accumulator split into 2 chains (ILP).
// Counted-vmcnt pipeline + setprio kept from R2.
// ---------------------------------------------------------------------------
__global__ __launch_bounds__(256, 2) void flash_mfma(
    const f16* __restrict__ Fpm, const f16* __restrict__ Fhm,
    const f16* __restrict__ Vth, const f16* __restrict__ Vtp,
    float* __restrict__ Out) {
  __shared__ f16 Kb[2][8192];  // raw copy of 32 swizzled F rows (16 KB)
  __shared__ f16 Vb[2][8192];  // raw copy of one Vt tile (16 KB)

  const int tid = threadIdx.x;
  const int wv = tid >> 6, lane = tid & 63;
  const int l32 = lane & 31, half = lane >> 5;

  const f16* Fq = Fpm;
  const f16* Fk = Fhm;
  const f16* Vt = Vth;
  float* O = Out;
  if (blockIdx.y) { Fq = Fhm; Fk = Fpm; Vt = Vtp; O = Out + (size_t)BB * LL * DD; }

  // XCD-locality swizzle (bijective): the 8 p-tiles of one batch share x%8.
  const int x = blockIdx.x;
  const int b = ((x & 7) << 2) | (x >> 6);
  const int p0 = ((x >> 3) & 7) * 128 + wv * 32;
  const int p = p0 + l32;  // this lane's p-column

  const f16* Fq_b = Fq + (size_t)b * LL * DD;
  const f16* Fk_b = Fk + (size_t)b * LL * DD;
  const f16* Vt_b = Vt + (size_t)b * LL * DD;  // tile-major [32][256][32]

  // Q fragments (B-operand): n=p, k=half*8+j; read through the F row-swizzle
  f16x8 qf[16];
  {
    const int qsw = p & 15;
#pragma unroll
    for (int s = 0; s < 16; ++s)
      qf[s] = *(const f16x8*)&Fq_b[(size_t)p * DD +
                                   (((2 * s + half) ^ qsw) << 3)];
  }

  float m_run = -1e30f, l_run = 0.f;
  f32x16 o[8];
#pragma unroll
  for (int t = 0; t < 8; ++t) o[t] = (f32x16)(0.f);

  const int ksw = l32 & 15;          // K frag chunk swizzle
  const int vsw = (l32 >> 1) & 3;    // V frag subchunk swizzle

  auto stage = [&](int buf, int T) {
#pragma unroll
    for (int ii = 0; ii < 4; ++ii) {
      int i = wv * 4 + ii;
      // rows {T*32+2i, +1}: 1 KB linear (F rows are chunk-swizzled in DRAM)
      async_copy16(Fk_b + (size_t)(T * 32 + 2 * i) * DD + lane * 8,
                   &Kb[buf][i * 512]);
    }
#pragma unroll
    for (int ii = 0; ii < 4; ++ii) {
      int i = wv * 4 + ii;
      // Vt tile T is 16 KB contiguous: pure linear copy
      async_copy16(Vt_b + (size_t)T * 8192 + i * 512 + lane * 8,
                   &Vb[buf][i * 512]);
    }
  };

  auto tile_compute = [&](int cur) {
    // S^T[q][p]: A = K frag (m=q), B = Q frag (n=p); 2 chains for ILP
    f32x16 S0 = (f32x16)(0.f), S1 = (f32x16)(0.f);
    __builtin_amdgcn_s_setprio(1);
#pragma unroll
    for (int s = 0; s < 16; s += 2) {
      f16x8 k0 = *(const f16x8*)&Kb[cur][(l32 << 8) +
                                         (((2 * s + half) ^ ksw) << 3)];
      S0 = __builtin_amdgcn_mfma_f32_32x32x16_f16(k0, qf[s], S0, 0, 0, 0);
      f16x8 k1 = *(const f16x8*)&Kb[cur][(l32 << 8) +
                                         (((2 * s + 2 + half) ^ ksw) << 3)];
      S1 = __builtin_amdgcn_mfma_f32_32x32x16_f16(k1, qf[s + 1], S1, 0, 0, 0);
    }
    __builtin_amdgcn_s_setprio(0);
    f32x16 S;
#pragma unroll
    for (int r = 0; r < 16; ++r) S[r] = S0[r] + S1[r];

    // in-lane softmax: lane holds 16 q-values of its p; merge with other half
    float mt = S[0];
#pragma unroll
    for (int r = 1; r < 16; ++r) mt = fmaxf(mt, S[r]);
    mt = fmaxf(mt, __shfl_xor(mt, 32, 64));

    // defer-max (T13): skip O-rescale while max growth <= 8
    const bool keep = __all((int)(mt - m_run <= 8.0f)) != 0;
    const float mn = keep ? m_run : fmaxf(m_run, mt);
    float pe[16];
    float ts = 0.f;
#pragma unroll
    for (int r = 0; r < 16; ++r) {
      pe[r] = __expf(S[r] - mn);
      ts += pe[r];
    }
    ts += __shfl_xor(ts, 32, 64);
    if (!keep) {
      const float alpha = __expf(m_run - mn);
      l_run *= alpha;
      m_run = mn;
#pragma unroll
      for (int t = 0; t < 8; ++t)
#pragma unroll
        for (int r = 0; r < 16; ++r) o[t][r] *= alpha;
    }
    l_run += ts;

    // build P^T B-frags: pack f16 pairs, exchange cross-half (4 shfl)
    u32 pw[8];
#pragma unroll
    for (int i = 0; i < 8; ++i) pw[i] = pack_pkrtz(pe[2 * i], pe[2 * i + 1]);
    u32 rc[4];
    {
      u32 s0 = half ? pw[0] : pw[2];
      u32 s1 = half ? pw[1] : pw[3];
      u32 s2 = half ? pw[4] : pw[6];
      u32 s3 = half ? pw[5] : pw[7];
      rc[0] = (u32)__shfl_xor((int)s0, 32, 64);
      rc[1] = (u32)__shfl_xor((int)s1, 32, 64);
      rc[2] = (u32)__shfl_xor((int)s2, 32, 64);
      rc[3] = (u32)__shfl_xor((int)s3, 32, 64);
    }
    f16x8 pf[2];
#pragma unroll
    for (int h = 0; h < 2; ++h) {
      u32 tmp[4];
      tmp[0] = half ? rc[2 * h] : pw[4 * h];
      tmp[1] = half ? rc[2 * h + 1] : pw[4 * h + 1];
      tmp[2] = half ? pw[4 * h + 2] : rc[2 * h];
      tmp[3] = half ? pw[4 * h + 3] : rc[2 * h + 1];
      __builtin_memcpy(&pf[h], tmp, 16);
    }

    // O^T += V^T P^T  (V frag: row d=t*32+l32, q-sub j=h*2+half at slot j^vsw)
    __builtin_amdgcn_s_setprio(1);
#pragma unroll
    for (int t = 0; t < 8; ++t) {
      int vrow = (t * 32 + l32) << 5;
      f16x8 v0 = *(const f16x8*)&Vb[cur][vrow + ((half ^ vsw) << 3)];
      o[t] = __builtin_amdgcn_mfma_f32_32x32x16_f16(v0, pf[0], o[t], 0, 0, 0);
      f16x8 v1 = *(const f16x8*)&Vb[cur][vrow + (((2 + half) ^ vsw) << 3)];
      o[t] = __builtin_amdgcn_mfma_f32_32x32x16_f16(v1, pf[1], o[t], 0, 0, 0);
    }
    __builtin_amdgcn_s_setprio(0);
  };

  stage(0, 0);  // 8 loads in flight
  int cur = 0;
  for (int it = 0; it < 31; ++it) {
    stage(cur ^ 1, it + 1);          // +8 in flight (prev end-barrier passed)
    VMCNT(8);                        // own tile-it loads done; next in flight
    __builtin_amdgcn_sched_barrier(0);
    __builtin_amdgcn_s_barrier();    // everyone's tile-it DMA landed
    tile_compute(cur);
    __builtin_amdgcn_s_barrier();    // all reads of buf[cur] done
    cur ^= 1;
  }
  VMCNT(0);
  __builtin_amdgcn_sched_barrier(0);
  __builtin_amdgcn_s_barrier();
  tile_compute(cur);
  __syncthreads();  // all waves done with Kb before epilogue overlay

  // epilogue: per 32x32 chunk, transpose via per-wave LDS tile (stride 36:
  // bank-balanced both sides), then 8 rows x 128B contiguous global stores.
  const float inv = 1.f / l_run;
  float* Tw = (float*)&Kb[0][0] + wv * (32 * 36);
  float* Ob = O + (size_t)b * LL * DD;
#pragma unroll
  for (int t = 0; t < 8; ++t) {
#pragma unroll
    for (int g = 0; g < 4; ++g) {
      int C = 2 * g + half;  // chunk idx 0..7 <-> global col t*32 + C*4
      f32x4 v;
      v[0] = o[t][4 * g + 0] * inv;
      v[1] = o[t][4 * g + 1] * inv;
      v[2] = o[t][4 * g + 2] * inv;
      v[3] = o[t][4 * g + 3] * inv;
      *(f32x4*)&Tw[l32 * 36 + C * 4] = v;
    }
    LGKMCNT0;
#pragma unroll
    for (int pass = 0; pass < 4; ++pass) {
      int row = pass * 8 + (lane >> 3);
      int Cr = lane & 7;
      f32x4 v = *(const f32x4*)&Tw[row * 36 + Cr * 4];
      *(f32x4*)&Ob[(size_t)(p0 + row) * DD + t * 32 + Cr * 4] = v;
    }
    LGKMCNT0;  // reads of this t done before next t's writes
  }
}

// ---------------------------------------------------------------------------
extern "C" void kernel_launch(void* const* d_in, const int* in_sizes, int n_in,
                              void* d_out, int out_size, void* d_ws,
                              size_t ws_size, hipStream_t stream) {
  const float* premises = (const float*)d_in[0];    // [32,1024,256] fp32
  const float* hypotheses = (const float*)d_in[1];  // [32,1024,256] fp32
  const float* W = (const float*)d_in[2];           // [256,256] fp32
  float* out = (float*)d_out;

  const size_t MF = (size_t)BB * LL * DD;
  f16* Fp = (f16*)d_ws;   // 16 MiB each; ws = 64 MiB exactly
  f16* Fh = Fp + MF;
  f16* Vth = Fh + MF;     // hypotheses^T, tile-major [B][32][256][32] f16
  f16* Vtp = Vth + MF;    // premises^T,   tile-major
  // Wt (131 KB) stashed in d_out tail: used only by proj, overwritten by flash
  f16* Wt = (f16*)((char*)d_out + (size_t)out_size * 4 - 256 * 256 * 2);

  // W^T -> f16
  transpose_to_f16<<<dim3(4, 4, 1), 256, 0, stream>>>(W, Wt, W, Wt, 256, 256, 1);
  // F = tanh(X @ W) (swizzled f16) + tile-major V^T emit
  proj_mfma<<<dim3(512, 1, 2), 256, 0, stream>>>(premises, hypotheses, Wt, Fp,
                                                 Fh, Vtp, Vth);
  // betas (y=0) and alphas (y=1): 256 blocks/direction, 2 blocks/CU exactly
  flash_mfma<<<dim3(256, 2), 256, 0, stream>>>(Fp, Fh, Vth, Vtp, out);
}

// Round 5
// 209.350 us; speedup vs baseline: 1.1533x; 1.1533x over previous
//
#include <hip/hip_runtime.h>

typedef _Float16 f16;
typedef __attribute__((ext_vector_type(4))) _Float16 f16x4;
typedef __attribute__((ext_vector_type(8))) _Float16 f16x8;
typedef __attribute__((ext_vector_type(4))) float f32x4;
typedef __attribute__((ext_vector_type(16))) float f32x16;
typedef unsigned int u32;

#define BB 32
#define LL 1024
#define DD 256

#define VMCNT(N) asm volatile("s_waitcnt vmcnt(" #N ")" ::: "memory")
#define LGKMCNT0 asm volatile("s_waitcnt lgkmcnt(0)" ::: "memory")

// async global->LDS, 16B per lane, dst = ldsbase + lane*16 (wave-uniform base)
__device__ __forceinline__ void async_copy16(const f16* g, f16* l) {
  __builtin_amdgcn_global_load_lds(
      (const __attribute__((address_space(1))) u32*)(const void*)g,
      (__attribute__((address_space(3))) u32*)(void*)l, 16, 0, 0);
}

// pack two f32 -> f16x2 in a u32 (v_cvt_pkrtz_f16_f32)
__device__ __forceinline__ u32 pack_pkrtz(float a, float b) {
  auto pk = __builtin_amdgcn_cvt_pkrtz(a, b);  // __fp16 ext_vector(2)
  u32 w;
  __builtin_memcpy(&w, &pk, 4);
  return w;
}

// ===========================================================================
// Scratch layouts (fragment-order, baked into DRAM):
//   F  [b][T=q>>5][s=d>>4][half=(d>>3)&1][l32=q&31][j=d&7]      (8192 f16/tile)
//   Vt [b][T=q>>5][t=d>>5][qh=(q>>4)&1][half=(q>>3)&1][l32=d&31][j=q&7]
//   WtF[N=n>>5][s=k>>4][half=(k>>3)&1][l32=n&31][j=k&7]
// Every producer store and consumer DMA is a linear 1-KB wave transaction;
// every LDS fragment read is &buf[frag*512 + lane*8] (lane-linear, conflict-
// free); flash Q / proj W fragment loads from global are contiguous 1 KB.
// ===========================================================================

// ---------------------------------------------------------------------------
// W[k][n] fp32 -> WtF fragment-order f16. 8 blocks (one per 32-col N-tile).
// ---------------------------------------------------------------------------
__global__ __launch_bounds__(256) void w_to_frag(const float* __restrict__ W,
                                                 f16* __restrict__ WtF) {
  __shared__ float T32[256][33];
  const int tid = threadIdx.x;
  const int N = blockIdx.x;
  const int nn = tid & 31, kr = tid >> 5;
#pragma unroll
  for (int p = 0; p < 32; ++p) {
    int k = p * 8 + kr;
    T32[k][nn] = W[(size_t)k * 256 + N * 32 + nn];
  }
  __syncthreads();
  const int wv = tid >> 6, lane = tid & 63;
  const int l32 = lane & 31, half = lane >> 5;
#pragma unroll
  for (int i = 0; i < 4; ++i) {
    int s = wv * 4 + i;
    f16x8 ov;
#pragma unroll
    for (int j = 0; j < 8; ++j) ov[j] = (f16)T32[s * 16 + half * 8 + j][l32];
    *(f16x8*)&WtF[(size_t)N * 8192 + s * 512 + lane * 8] = ov;
  }
}

// ---------------------------------------------------------------------------
// Projection: F = tanh(A @ W) + V^T emit, both in fragment-order layouts.
// 33 KB LDS (A tile only; W frags are contiguous 1-KB L2 loads), 3 barriers,
// 3 blocks/CU. Block = 4 waves (2m x 2n), 64m x 256n, MFMA 32x32x16.
// ---------------------------------------------------------------------------
__global__ __launch_bounds__(256, 3) void proj_mfma(
    const float* __restrict__ Pin, const float* __restrict__ Hin,
    const f16* __restrict__ WtF, f16* __restrict__ Fp, f16* __restrict__ Fh,
    f16* __restrict__ Vtp, f16* __restrict__ Vth) {
  __shared__ f16 As[64][264];  // 33 KB; 16-B aligned rows
  const int tid = threadIdx.x;
  const int wv = tid >> 6, lane = tid & 63;
  const int l32 = lane & 31, half = lane >> 5;
  const int wm = wv >> 1, wn = wv & 1;
  const float* A = blockIdx.z ? Hin : Pin;
  f16* F = blockIdx.z ? Fh : Fp;
  f16* VtO = blockIdx.z ? Vth : Vtp;
  const int m0 = blockIdx.x * 64;
  const int T0 = m0 >> 5;  // global tile index (= b*32 + local tile)

  // stage full A tile (64 x 256) fp32 -> f16, coalesced rows
  {
    const int r = tid >> 4;         // 0..15
    const int c4 = (tid & 15) * 4;  // 0..60
#pragma unroll
    for (int pp = 0; pp < 4; ++pp)
#pragma unroll
      for (int ch = 0; ch < 4; ++ch) {
        float4 v =
            *(const float4*)&A[(size_t)(m0 + r + pp * 16) * 256 + ch * 64 + c4];
        f16x4 h4;
        h4[0] = (f16)v.x; h4[1] = (f16)v.y; h4[2] = (f16)v.z; h4[3] = (f16)v.w;
        *(f16x4*)&As[r + pp * 16][ch * 64 + c4] = h4;
      }
  }
  __syncthreads();

  // hoist all 16 A-frags (32x32x16: m = wm*32+l32, k = ks*16+half*8+j)
  f16x8 af[16];
#pragma unroll
  for (int ks = 0; ks < 16; ++ks)
    af[ks] = *(const f16x8*)&As[wm * 32 + l32][ks * 16 + half * 8];

  // V^T emit (raw converted A), fragment-order: 8 linear 1-KB stores/wave
  {
#pragma unroll
    for (int i = 0; i < 8; ++i) {
      int idx = wv * 8 + i;               // 0..31
      int Tl = idx >> 4;                  // 0..1
      int t = (idx >> 1) & 7;             // 0..7 (d group)
      int qh = idx & 1;                   // 0..1 (q group)
      int qb = Tl * 32 + qh * 16 + half * 8;
      f16x8 ov;
#pragma unroll
      for (int j = 0; j < 8; ++j) ov[j] = As[qb + j][t * 32 + l32];
      *(f16x8*)&VtO[(size_t)(T0 + Tl) * 8192 + t * 1024 + qh * 512 +
                    half * 256 + l32 * 8] = ov;
    }
  }
  __syncthreads();  // all As reads done before tanh-bounce overwrite

  // nc loop: W frags contiguous from L2, MFMA, tanh -> As bounce (no barriers)
#pragma unroll
  for (int nc = 0; nc < 4; ++nc) {
    f32x16 acc = (f32x16)(0.f);
#pragma unroll
    for (int ks = 0; ks < 16; ++ks) {
      f16x8 wf = *(const f16x8*)&WtF[(size_t)nc * 16384 + wn * 8192 +
                                     ks * 512 + lane * 8];
      acc = __builtin_amdgcn_mfma_f32_32x32x16_f16(af[ks], wf, acc, 0, 0, 0);
    }
#pragma unroll
    for (int r = 0; r < 16; ++r) {
      float xv = acc[r];
      float e2 = __expf(2.f * xv);
      float th = 1.f - 2.f / (e2 + 1.f);
      As[wm * 32 + (r & 3) + 8 * (r >> 2) + 4 * half]
        [nc * 64 + wn * 32 + l32] = (f16)th;
    }
  }
  __syncthreads();

  // F store, fragment-order: 8 linear 1-KB stores/wave
#pragma unroll
  for (int i = 0; i < 8; ++i) {
    int idx = wv * 8 + i;  // 0..31
    int Tl = idx >> 4;     // 0..1
    int s = idx & 15;      // 0..15
    f16x8 ov = *(const f16x8*)&As[Tl * 32 + l32][s * 16 + half * 8];
    *(f16x8*)&F[(size_t)(T0 + Tl) * 8192 + s * 512 + half * 256 + l32 * 8] =
        ov;
  }
}

// ---------------------------------------------------------------------------
// Flash alignment, 32x32x16 MFMA, transposed formulation:
//   S^T = K Q^T  (A=K frags from LDS, B=Q frags in regs)
//   O^T = V^T P^T (A=V^T frags from LDS, B=P^T built by cross-half shuffle)
// Fragment-order scratch: staging = pure linear 16-KB tile DMA; ALL LDS
// fragment reads lane-linear (&buf[frag*512+lane*8], conflict-free).
// Counted-vmcnt pipeline + setprio + defer-max + ILP-split kept.
// ---------------------------------------------------------------------------
__global__ __launch_bounds__(256, 2) void flash_mfma(
    const f16* __restrict__ Fpm, const f16* __restrict__ Fhm,
    const f16* __restrict__ Vth, const f16* __restrict__ Vtp,
    float* __restrict__ Out) {
  __shared__ f16 Kb[2][8192];  // one K tile (fragment-order)
  __shared__ f16 Vb[2][8192];  // one V tile (fragment-order)

  const int tid = threadIdx.x;
  const int wv = tid >> 6, lane = tid & 63;
  const int l32 = lane & 31, half = lane >> 5;

  const f16* Fq = Fpm;
  const f16* Fk = Fhm;
  const f16* Vt = Vth;
  float* O = Out;
  if (blockIdx.y) { Fq = Fhm; Fk = Fpm; Vt = Vtp; O = Out + (size_t)BB * LL * DD; }

  // XCD-locality swizzle (bijective): the 8 p-tiles of one batch share x%8.
  const int x = blockIdx.x;
  const int b = ((x & 7) << 2) | (x >> 6);
  const int p0 = ((x >> 3) & 7) * 128 + wv * 32;
  const int p = p0 + l32;  // this lane's p-column

  const f16* Fq_b = Fq + (size_t)b * LL * DD;
  const f16* Fk_b = Fk + (size_t)b * LL * DD;
  const f16* Vt_b = Vt + (size_t)b * LL * DD;

  // Q fragments (B-operand): n=p, k=s*16+half*8+j; contiguous 1 KB per wave
  f16x8 qf[16];
  {
    const f16* qt = Fq_b + (size_t)(p >> 5) * 8192 + half * 256 + (p & 31) * 8;
#pragma unroll
    for (int s = 0; s < 16; ++s) qf[s] = *(const f16x8*)&qt[s * 512];
  }

  float m_run = -1e30f, l_run = 0.f;
  f32x16 o[8];
#pragma unroll
  for (int t = 0; t < 8; ++t) o[t] = (f32x16)(0.f);

  auto stage = [&](int buf, int T) {
    const f16* kt = Fk_b + (size_t)T * 8192;
    const f16* vt = Vt_b + (size_t)T * 8192;
#pragma unroll
    for (int ii = 0; ii < 4; ++ii) {
      int i = wv * 4 + ii;
      async_copy16(kt + i * 512 + lane * 8, &Kb[buf][i * 512]);
    }
#pragma unroll
    for (int ii = 0; ii < 4; ++ii) {
      int i = wv * 4 + ii;
      async_copy16(vt + i * 512 + lane * 8, &Vb[buf][i * 512]);
    }
  };

  auto tile_compute = [&](int cur) {
    // S^T[q][p]: A = K frag (m=q), B = Q frag (n=p); 2 chains for ILP
    f32x16 S0 = (f32x16)(0.f), S1 = (f32x16)(0.f);
    __builtin_amdgcn_s_setprio(1);
#pragma unroll
    for (int s = 0; s < 16; s += 2) {
      f16x8 k0 = *(const f16x8*)&Kb[cur][s * 512 + lane * 8];
      S0 = __builtin_amdgcn_mfma_f32_32x32x16_f16(k0, qf[s], S0, 0, 0, 0);
      f16x8 k1 = *(const f16x8*)&Kb[cur][(s + 1) * 512 + lane * 8];
      S1 = __builtin_amdgcn_mfma_f32_32x32x16_f16(k1, qf[s + 1], S1, 0, 0, 0);
    }
    __builtin_amdgcn_s_setprio(0);
    f32x16 S;
#pragma unroll
    for (int r = 0; r < 16; ++r) S[r] = S0[r] + S1[r];

    // in-lane softmax: lane holds 16 q-values of its p; merge with other half
    float mt = S[0];
#pragma unroll
    for (int r = 1; r < 16; ++r) mt = fmaxf(mt, S[r]);
    mt = fmaxf(mt, __shfl_xor(mt, 32, 64));

    // defer-max (T13): skip O-rescale while max growth <= 8
    const bool keep = __all((int)(mt - m_run <= 8.0f)) != 0;
    const float mn = keep ? m_run : fmaxf(m_run, mt);
    float pe[16];
    float ts = 0.f;
#pragma unroll
    for (int r = 0; r < 16; ++r) {
      pe[r] = __expf(S[r] - mn);
      ts += pe[r];
    }
    ts += __shfl_xor(ts, 32, 64);
    if (!keep) {
      const float alpha = __expf(m_run - mn);
      l_run *= alpha;
      m_run = mn;
#pragma unroll
      for (int t = 0; t < 8; ++t)
#pragma unroll
        for (int r = 0; r < 16; ++r) o[t][r] *= alpha;
    }
    l_run += ts;

    // build P^T B-frags: pack f16 pairs, exchange cross-half (4 shfl)
    u32 pw[8];
#pragma unroll
    for (int i = 0; i < 8; ++i) pw[i] = pack_pkrtz(pe[2 * i], pe[2 * i + 1]);
    u32 rc[4];
    {
      u32 s0 = half ? pw[0] : pw[2];
      u32 s1 = half ? pw[1] : pw[3];
      u32 s2 = half ? pw[4] : pw[6];
      u32 s3 = half ? pw[5] : pw[7];
      rc[0] = (u32)__shfl_xor((int)s0, 32, 64);
      rc[1] = (u32)__shfl_xor((int)s1, 32, 64);
      rc[2] = (u32)__shfl_xor((int)s2, 32, 64);
      rc[3] = (u32)__shfl_xor((int)s3, 32, 64);
    }
    f16x8 pf[2];
#pragma unroll
    for (int h = 0; h < 2; ++h) {
      u32 tmp[4];
      tmp[0] = half ? rc[2 * h] : pw[4 * h];
      tmp[1] = half ? rc[2 * h + 1] : pw[4 * h + 1];
      tmp[2] = half ? pw[4 * h + 2] : rc[2 * h];
      tmp[3] = half ? pw[4 * h + 3] : rc[2 * h + 1];
      __builtin_memcpy(&pf[h], tmp, 16);
    }

    // O^T += V^T P^T (V frag: m=d=t*32+l32, k-group qh -> lane-linear)
    __builtin_amdgcn_s_setprio(1);
#pragma unroll
    for (int t = 0; t < 8; ++t) {
      f16x8 v0 = *(const f16x8*)&Vb[cur][t * 1024 + lane * 8];
      o[t] = __builtin_amdgcn_mfma_f32_32x32x16_f16(v0, pf[0], o[t], 0, 0, 0);
      f16x8 v1 = *(const f16x8*)&Vb[cur][t * 1024 + 512 + lane * 8];
      o[t] = __builtin_amdgcn_mfma_f32_32x32x16_f16(v1, pf[1], o[t], 0, 0, 0);
    }
    __builtin_amdgcn_s_setprio(0);
  };

  stage(0, 0);  // 8 loads in flight per wave
  int cur = 0;
  for (int it = 0; it < 31; ++it) {
    stage(cur ^ 1, it + 1);          // +8 in flight (prev end-barrier passed)
    VMCNT(8);                        // own tile-it loads done; next in flight
    __builtin_amdgcn_sched_barrier(0);
    __builtin_amdgcn_s_barrier();    // everyone's tile-it DMA landed
    tile_compute(cur);
    __builtin_amdgcn_s_barrier();    // all reads of buf[cur] done
    cur ^= 1;
  }
  VMCNT(0);
  __builtin_amdgcn_sched_barrier(0);
  __builtin_amdgcn_s_barrier();
  tile_compute(cur);
  __syncthreads();  // all waves done with Kb before epilogue overlay

  // epilogue: per 32x32 chunk, transpose via per-wave LDS tile (stride 36:
  // bank-balanced both sides), then 8 rows x 128B contiguous global stores.
  const float inv = 1.f / l_run;
  float* Tw = (float*)&Kb[0][0] + wv * (32 * 36);
  float* Ob = O + (size_t)b * LL * DD;
#pragma unroll
  for (int t = 0; t < 8; ++t) {
#pragma unroll
    for (int g = 0; g < 4; ++g) {
      int C = 2 * g + half;  // chunk idx 0..7 <-> global col t*32 + C*4
      f32x4 v;
      v[0] = o[t][4 * g + 0] * inv;
      v[1] = o[t][4 * g + 1] * inv;
      v[2] = o[t][4 * g + 2] * inv;
      v[3] = o[t][4 * g + 3] * inv;
      *(f32x4*)&Tw[l32 * 36 + C * 4] = v;
    }
    LGKMCNT0;
#pragma unroll
    for (int pass = 0; pass < 4; ++pass) {
      int row = pass * 8 + (lane >> 3);
      int Cr = lane & 7;
      f32x4 v = *(const f32x4*)&Tw[row * 36 + Cr * 4];
      *(f32x4*)&Ob[(size_t)(p0 + row) * DD + t * 32 + Cr * 4] = v;
    }
    LGKMCNT0;  // reads of this t done before next t's writes
  }
}

// ---------------------------------------------------------------------------
extern "C" void kernel_launch(void* const* d_in, const int* in_sizes, int n_in,
                              void* d_out, int out_size, void* d_ws,
                              size_t ws_size, hipStream_t stream) {
  const float* premises = (const float*)d_in[0];    // [32,1024,256] fp32
  const float* hypotheses = (const float*)d_in[1];  // [32,1024,256] fp32
  const float* W = (const float*)d_in[2];           // [256,256] fp32
  float* out = (float*)d_out;

  const size_t MF = (size_t)BB * LL * DD;
  f16* Fp = (f16*)d_ws;   // 16 MiB each; ws = 64 MiB exactly
  f16* Fh = Fp + MF;
  f16* Vth = Fh + MF;     // hypotheses^T, fragment-order tiles
  f16* Vtp = Vth + MF;    // premises^T,   fragment-order tiles
  // WtF (131 KB) stashed in d_out tail: used only by proj, overwritten by flash
  f16* WtF = (f16*)((char*)d_out + (size_t)out_size * 4 - 256 * 256 * 2);

  // W -> fragment-order f16 W^T
  w_to_frag<<<dim3(8), 256, 0, stream>>>(W, WtF);
  // F = tanh(X @ W) + V^T emit (fragment-order)
  proj_mfma<<<dim3(512, 1, 2), 256, 0, stream>>>(premises, hypotheses, WtF, Fp,
                                                 Fh, Vtp, Vth);
  // betas (y=0) and alphas (y=1): 256 blocks/direction, 2 blocks/CU exactly
  flash_mfma<<<dim3(256, 2), 256, 0, stream>>>(Fp, Fh, Vth, Vtp, out);
}

// Round 6
// 205.378 us; speedup vs baseline: 1.1756x; 1.0193x over previous
//
#include <hip/hip_runtime.h>

typedef _Float16 f16;
typedef __attribute__((ext_vector_type(4))) _Float16 f16x4;
typedef __attribute__((ext_vector_type(8))) _Float16 f16x8;
typedef __attribute__((ext_vector_type(4))) float f32x4;
typedef __attribute__((ext_vector_type(16))) float f32x16;
typedef unsigned int u32;

#define BB 32
#define LL 1024
#define DD 256

#define VMCNT(N) asm volatile("s_waitcnt vmcnt(" #N ")" ::: "memory")
#define LGKMCNT0 asm volatile("s_waitcnt lgkmcnt(0)" ::: "memory")

// async global->LDS, 16B per lane, dst = ldsbase + lane*16 (wave-uniform base)
__device__ __forceinline__ void async_copy16(const f16* g, f16* l) {
  __builtin_amdgcn_global_load_lds(
      (const __attribute__((address_space(1))) u32*)(const void*)g,
      (__attribute__((address_space(3))) u32*)(void*)l, 16, 0, 0);
}

// pack two f32 -> f16x2 in a u32 (v_cvt_pkrtz_f16_f32)
__device__ __forceinline__ u32 pack_pkrtz(float a, float b) {
  auto pk = __builtin_amdgcn_cvt_pkrtz(a, b);  // __fp16 ext_vector(2)
  u32 w;
  __builtin_memcpy(&w, &pk, 4);
  return w;
}

// ===========================================================================
// Scratch layouts (fragment-order, baked into DRAM):
//   F  [b][T=q>>5][s=d>>4][half=(d>>3)&1][l32=q&31][j=d&7]      (8192 f16/tile)
//   Vt [b][T=q>>5][t=d>>5][qh=(q>>4)&1][half=(q>>3)&1][l32=d&31][j=q&7]
//   WtF[N=n>>5][s=k>>4][half=(k>>3)&1][l32=n&31][j=k&7]
// Every producer store and consumer DMA is a linear 1-KB wave transaction;
// every LDS fragment read is &buf[frag*512 + lane*8] (lane-linear, conflict-
// free); flash Q / proj W fragment loads from global are contiguous 1 KB.
// ===========================================================================

// ---------------------------------------------------------------------------
// W[k][n] fp32 -> WtF fragment-order f16. 8 blocks (one per 32-col N-tile).
// ---------------------------------------------------------------------------
__global__ __launch_bounds__(256) void w_to_frag(const float* __restrict__ W,
                                                 f16* __restrict__ WtF) {
  __shared__ float T32[256][33];
  const int tid = threadIdx.x;
  const int N = blockIdx.x;
  const int nn = tid & 31, kr = tid >> 5;
#pragma unroll
  for (int p = 0; p < 32; ++p) {
    int k = p * 8 + kr;
    T32[k][nn] = W[(size_t)k * 256 + N * 32 + nn];
  }
  __syncthreads();
  const int wv = tid >> 6, lane = tid & 63;
  const int l32 = lane & 31, half = lane >> 5;
#pragma unroll
  for (int i = 0; i < 4; ++i) {
    int s = wv * 4 + i;
    f16x8 ov;
#pragma unroll
    for (int j = 0; j < 8; ++j) ov[j] = (f16)T32[s * 16 + half * 8 + j][l32];
    *(f16x8*)&WtF[(size_t)N * 8192 + s * 512 + lane * 8] = ov;
  }
}

// ---------------------------------------------------------------------------
// Projection: F = tanh(A @ W) + V^T emit, both in fragment-order layouts.
// 33 KB LDS (A tile only; W frags are contiguous 1-KB L2 loads), 3 barriers,
// 3 blocks/CU. Block = 4 waves (2m x 2n), 64m x 256n, MFMA 32x32x16.
// (unchanged from R5 -- flash rewrite this round; proj counters next round)
// ---------------------------------------------------------------------------
__global__ __launch_bounds__(256, 3) void proj_mfma(
    const float* __restrict__ Pin, const float* __restrict__ Hin,
    const f16* __restrict__ WtF, f16* __restrict__ Fp, f16* __restrict__ Fh,
    f16* __restrict__ Vtp, f16* __restrict__ Vth) {
  __shared__ f16 As[64][264];  // 33 KB; 16-B aligned rows
  const int tid = threadIdx.x;
  const int wv = tid >> 6, lane = tid & 63;
  const int l32 = lane & 31, half = lane >> 5;
  const int wm = wv >> 1, wn = wv & 1;
  const float* A = blockIdx.z ? Hin : Pin;
  f16* F = blockIdx.z ? Fh : Fp;
  f16* VtO = blockIdx.z ? Vth : Vtp;
  const int m0 = blockIdx.x * 64;
  const int T0 = m0 >> 5;  // global tile index (= b*32 + local tile)

  // stage full A tile (64 x 256) fp32 -> f16, coalesced rows
  {
    const int r = tid >> 4;         // 0..15
    const int c4 = (tid & 15) * 4;  // 0..60
#pragma unroll
    for (int pp = 0; pp < 4; ++pp)
#pragma unroll
      for (int ch = 0; ch < 4; ++ch) {
        float4 v =
            *(const float4*)&A[(size_t)(m0 + r + pp * 16) * 256 + ch * 64 + c4];
        f16x4 h4;
        h4[0] = (f16)v.x; h4[1] = (f16)v.y; h4[2] = (f16)v.z; h4[3] = (f16)v.w;
        *(f16x4*)&As[r + pp * 16][ch * 64 + c4] = h4;
      }
  }
  __syncthreads();

  // hoist all 16 A-frags (32x32x16: m = wm*32+l32, k = ks*16+half*8+j)
  f16x8 af[16];
#pragma unroll
  for (int ks = 0; ks < 16; ++ks)
    af[ks] = *(const f16x8*)&As[wm * 32 + l32][ks * 16 + half * 8];

  // V^T emit (raw converted A), fragment-order: 8 linear 1-KB stores/wave
  {
#pragma unroll
    for (int i = 0; i < 8; ++i) {
      int idx = wv * 8 + i;               // 0..31
      int Tl = idx >> 4;                  // 0..1
      int t = (idx >> 1) & 7;             // 0..7 (d group)
      int qh = idx & 1;                   // 0..1 (q group)
      int qb = Tl * 32 + qh * 16 + half * 8;
      f16x8 ov;
#pragma unroll
      for (int j = 0; j < 8; ++j) ov[j] = As[qb + j][t * 32 + l32];
      *(f16x8*)&VtO[(size_t)(T0 + Tl) * 8192 + t * 1024 + qh * 512 +
                    half * 256 + l32 * 8] = ov;
    }
  }
  __syncthreads();  // all As reads done before tanh-bounce overwrite

  // nc loop: W frags contiguous from L2, MFMA, tanh -> As bounce (no barriers)
#pragma unroll
  for (int nc = 0; nc < 4; ++nc) {
    f32x16 acc = (f32x16)(0.f);
#pragma unroll
    for (int ks = 0; ks < 16; ++ks) {
      f16x8 wf = *(const f16x8*)&WtF[(size_t)nc * 16384 + wn * 8192 +
                                     ks * 512 + lane * 8];
      acc = __builtin_amdgcn_mfma_f32_32x32x16_f16(af[ks], wf, acc, 0, 0, 0);
    }
#pragma unroll
    for (int r = 0; r < 16; ++r) {
      float xv = acc[r];
      float e2 = __expf(2.f * xv);
      float th = 1.f - 2.f / (e2 + 1.f);
      As[wm * 32 + (r & 3) + 8 * (r >> 2) + 4 * half]
        [nc * 64 + wn * 32 + l32] = (f16)th;
    }
  }
  __syncthreads();

  // F store, fragment-order: 8 linear 1-KB stores/wave
#pragma unroll
  for (int i = 0; i < 8; ++i) {
    int idx = wv * 8 + i;  // 0..31
    int Tl = idx >> 4;     // 0..1
    int s = idx & 15;      // 0..15
    f16x8 ov = *(const f16x8*)&As[Tl * 32 + l32][s * 16 + half * 8];
    *(f16x8*)&F[(size_t)(T0 + Tl) * 8192 + s * 512 + half * 256 + l32 * 8] =
        ov;
  }
}

// ---------------------------------------------------------------------------
// Flash alignment, 32x32x16 MFMA, transposed formulation.
// NEW (this round): 8-wave 512-thr blocks covering 256 p-rows (halves K/V
// staging traffic 512->256 MiB); within-wave software pipeline: QK(it+1)
// issued BEFORE softmax(it)+PV(it) (S readout one iteration after its MFMA
// chain -> latency hidden; softmax VALU overlaps QK MFMA pipe); staging
// split K-early / V-late with counted vmcnt (<=4 outstanding, wait-to-2).
// Register-neutral vs R5: dual-chain S0/S1 replaced by Scur/Snext.
// ---------------------------------------------------------------------------
__global__ __launch_bounds__(512, 2) void flash_mfma(
    const f16* __restrict__ Fpm, const f16* __restrict__ Fhm,
    const f16* __restrict__ Vth, const f16* __restrict__ Vtp,
    float* __restrict__ Out) {
  __shared__ f16 SMEM[4][8192];  // [0..1] K dbuf, [2..3] V dbuf (64 KB)

  const int tid = threadIdx.x;
  const int wv = tid >> 6, lane = tid & 63;
  const int l32 = lane & 31, half = lane >> 5;

  const f16* Fq = Fpm;
  const f16* Fk = Fhm;
  const f16* Vt = Vth;
  float* O = Out;
  if (blockIdx.y) { Fq = Fhm; Fk = Fpm; Vt = Vtp; O = Out + (size_t)BB * LL * DD; }

  // XCD swizzle: x = ((b>>3)*4 + pblk)*8 + (b&7) -> all 4 p-blocks of a
  // batch share x%8 (one XCD residue class). Bijective on 0..127.
  const int x = blockIdx.x;
  const int b = ((x >> 5) << 3) | (x & 7);
  const int pblk = (x >> 3) & 3;
  const int p0 = pblk * 256 + wv * 32;
  const int p = p0 + l32;  // this lane's p-column

  const f16* Fq_b = Fq + (size_t)b * LL * DD;
  const f16* Fk_b = Fk + (size_t)b * LL * DD;
  const f16* Vt_b = Vt + (size_t)b * LL * DD;

  // Q fragments (B-operand): n=p, k=s*16+half*8+j; contiguous 1 KB per wave
  f16x8 qf[16];
  {
    const f16* qt = Fq_b + (size_t)(p >> 5) * 8192 + half * 256 + (p & 31) * 8;
#pragma unroll
    for (int s = 0; s < 16; ++s) qf[s] = *(const f16x8*)&qt[s * 512];
  }

  float m_run = -1e30f, l_run = 0.f;
  f32x16 o[8];
#pragma unroll
  for (int t = 0; t < 8; ++t) o[t] = (f32x16)(0.f);

  // wave wv stages K sections {2wv, 2wv+1} and V sections {2wv, 2wv+1}
  auto stage_K = [&](int buf, int T) {
    const f16* kt = Fk_b + (size_t)T * 8192 + wv * 1024 + lane * 8;
    async_copy16(kt, &SMEM[buf][wv * 1024]);
    async_copy16(kt + 512, &SMEM[buf][wv * 1024 + 512]);
  };
  auto stage_V = [&](int buf, int T) {
    const f16* vt = Vt_b + (size_t)T * 8192 + wv * 1024 + lane * 8;
    async_copy16(vt, &SMEM[2 + buf][wv * 1024]);
    async_copy16(vt + 512, &SMEM[2 + buf][wv * 1024 + 512]);
  };

  // QK^T: single 16-MFMA chain (result read one iteration later)
  auto qk16 = [&](int buf) {
    f32x16 S = (f32x16)(0.f);
    __builtin_amdgcn_s_setprio(1);
#pragma unroll
    for (int s = 0; s < 16; ++s) {
      f16x8 kf = *(const f16x8*)&SMEM[buf][s * 512 + lane * 8];
      S = __builtin_amdgcn_mfma_f32_32x32x16_f16(kf, qf[s], S, 0, 0, 0);
    }
    __builtin_amdgcn_s_setprio(0);
    return S;
  };

  // softmax(S) -> pf[2] B-frags; updates m_run/l_run and rescales o
  f16x8 pf[2];
  auto softmax_pack = [&](const f32x16& S) {
    float mt = S[0];
#pragma unroll
    for (int r = 1; r < 16; ++r) mt = fmaxf(mt, S[r]);
    mt = fmaxf(mt, __shfl_xor(mt, 32, 64));
    const bool keep = __all((int)(mt - m_run <= 8.0f)) != 0;  // defer-max
    const float mn = keep ? m_run : fmaxf(m_run, mt);
    float pe[16];
    float ts = 0.f;
#pragma unroll
    for (int r = 0; r < 16; ++r) {
      pe[r] = __expf(S[r] - mn);
      ts += pe[r];
    }
    ts += __shfl_xor(ts, 32, 64);
    if (!keep) {
      const float alpha = __expf(m_run - mn);
      l_run *= alpha;
      m_run = mn;
#pragma unroll
      for (int t = 0; t < 8; ++t)
#pragma unroll
        for (int r = 0; r < 16; ++r) o[t][r] *= alpha;
    }
    l_run += ts;

    u32 pw[8];
#pragma unroll
    for (int i = 0; i < 8; ++i) pw[i] = pack_pkrtz(pe[2 * i], pe[2 * i + 1]);
    u32 rc[4];
    {
      u32 s0 = half ? pw[0] : pw[2];
      u32 s1 = half ? pw[1] : pw[3];
      u32 s2 = half ? pw[4] : pw[6];
      u32 s3 = half ? pw[5] : pw[7];
      rc[0] = (u32)__shfl_xor((int)s0, 32, 64);
      rc[1] = (u32)__shfl_xor((int)s1, 32, 64);
      rc[2] = (u32)__shfl_xor((int)s2, 32, 64);
      rc[3] = (u32)__shfl_xor((int)s3, 32, 64);
    }
#pragma unroll
    for (int h = 0; h < 2; ++h) {
      u32 tmp[4];
      tmp[0] = half ? rc[2 * h] : pw[4 * h];
      tmp[1] = half ? rc[2 * h + 1] : pw[4 * h + 1];
      tmp[2] = half ? pw[4 * h + 2] : rc[2 * h];
      tmp[3] = half ? pw[4 * h + 3] : rc[2 * h + 1];
      __builtin_memcpy(&pf[h], tmp, 16);
    }
  };

  auto pv = [&](int buf) {
    __builtin_amdgcn_s_setprio(1);
#pragma unroll
    for (int t = 0; t < 8; ++t) {
      f16x8 v0 = *(const f16x8*)&SMEM[2 + buf][t * 1024 + lane * 8];
      o[t] = __builtin_amdgcn_mfma_f32_32x32x16_f16(v0, pf[0], o[t], 0, 0, 0);
      f16x8 v1 = *(const f16x8*)&SMEM[2 + buf][t * 1024 + 512 + lane * 8];
      o[t] = __builtin_amdgcn_mfma_f32_32x32x16_f16(v1, pf[1], o[t], 0, 0, 0);
    }
    __builtin_amdgcn_s_setprio(0);
  };

  // prologue: tile0 K+V, tile1 K in flight; wait tile0 (leave K1 in flight)
  stage_K(0, 0);
  stage_V(0, 0);
  stage_K(1, 1);
  VMCNT(2);
  __builtin_amdgcn_sched_barrier(0);
  __builtin_amdgcn_s_barrier();
  f32x16 Scur = qk16(0);
  stage_V(1, 1);

  for (int it = 0; it < 31; ++it) {
    const int cur = it & 1, nxt = cur ^ 1;
    // K(it+2) into buf cur: K region dead since QK(it) (all waves, prev BAR2)
    if (it < 30) {
      stage_K(cur, it + 2);
      VMCNT(2);  // outstanding: V(it+1)[2] + K(it+2)[2] -> tile it+1 landed
    } else {
      VMCNT(0);  // drain: tile 31 fully landed
    }
    __builtin_amdgcn_sched_barrier(0);
    __builtin_amdgcn_s_barrier();  // tile it+1 ready for ALL waves
    f32x16 Snext = qk16(nxt);      // MFMA pipe crunches while VALU below runs
    softmax_pack(Scur);            // softmax of tile it (S from prev iter)
    pv(cur);                       // O += V(it) P(it)
    __builtin_amdgcn_s_barrier();  // all waves done reading V(it)
    if (it < 30) stage_V(cur, it + 2);  // V region of buf cur now free
    Scur = Snext;
  }
  // tail: tile 31 (in buf 1)
  softmax_pack(Scur);
  pv(1);
  __syncthreads();  // all waves done with SMEM before epilogue overlay

  // epilogue: per 32x32 chunk, transpose via per-wave LDS tile (stride 36:
  // bank-balanced both sides), then 8 rows x 128B contiguous global stores.
  const float inv = 1.f / l_run;
  float* Tw = (float*)&SMEM[0][0] + wv * (32 * 36);
  float* Ob = O + (size_t)b * LL * DD;
#pragma unroll
  for (int t = 0; t < 8; ++t) {
#pragma unroll
    for (int g = 0; g < 4; ++g) {
      int C = 2 * g + half;  // chunk idx 0..7 <-> global col t*32 + C*4
      f32x4 v;
      v[0] = o[t][4 * g + 0] * inv;
      v[1] = o[t][4 * g + 1] * inv;
      v[2] = o[t][4 * g + 2] * inv;
      v[3] = o[t][4 * g + 3] * inv;
      *(f32x4*)&Tw[l32 * 36 + C * 4] = v;
    }
    LGKMCNT0;
#pragma unroll
    for (int pass = 0; pass < 4; ++pass) {
      int row = pass * 8 + (lane >> 3);
      int Cr = lane & 7;
      f32x4 v = *(const f32x4*)&Tw[row * 36 + Cr * 4];
      *(f32x4*)&Ob[(size_t)(p0 + row) * DD + t * 32 + Cr * 4] = v;
    }
    LGKMCNT0;  // reads of this t done before next t's writes
  }
}

// ---------------------------------------------------------------------------
extern "C" void kernel_launch(void* const* d_in, const int* in_sizes, int n_in,
                              void* d_out, int out_size, void* d_ws,
                              size_t ws_size, hipStream_t stream) {
  const float* premises = (const float*)d_in[0];    // [32,1024,256] fp32
  const float* hypotheses = (const float*)d_in[1];  // [32,1024,256] fp32
  const float* W = (const float*)d_in[2];           // [256,256] fp32
  float* out = (float*)d_out;

  const size_t MF = (size_t)BB * LL * DD;
  f16* Fp = (f16*)d_ws;   // 16 MiB each; ws = 64 MiB exactly
  f16* Fh = Fp + MF;
  f16* Vth = Fh + MF;     // hypotheses^T, fragment-order tiles
  f16* Vtp = Vth + MF;    // premises^T,   fragment-order tiles
  // WtF (131 KB) stashed in d_out tail: used only by proj, overwritten by flash
  f16* WtF = (f16*)((char*)d_out + (size_t)out_size * 4 - 256 * 256 * 2);

  // W -> fragment-order f16 W^T
  w_to_frag<<<dim3(8), 256, 0, stream>>>(W, WtF);
  // F = tanh(X @ W) + V^T emit (fragment-order)
  proj_mfma<<<dim3(512, 1, 2), 256, 0, stream>>>(premises, hypotheses, WtF, Fp,
                                                 Fh, Vtp, Vth);
  // betas (y=0) and alphas (y=1): 64 blocks/dir-quadrant -> 256 total, 1/CU
  flash_mfma<<<dim3(128, 2), 512, 0, stream>>>(Fp, Fh, Vth, Vtp, out);
}